// Round 10
// baseline (157.512 us; speedup 1.0000x reference)
//
#include <hip/hip_runtime.h>
#include <math.h>

typedef float f32x4 __attribute__((ext_vector_type(4)));
typedef short bf16x8 __attribute__((ext_vector_type(8)));
typedef unsigned short u16;

__device__ __forceinline__ u16 f2bf(float f) {
    unsigned u = __builtin_bit_cast(unsigned, f);
    u += 0x7fff + ((u >> 16) & 1);   // RNE
    return (u16)(u >> 16);
}
__device__ __forceinline__ float bf2f(u16 s) {
    unsigned v = ((unsigned)s) << 16;
    return __builtin_bit_cast(float, v);
}
__device__ __forceinline__ void gload16(const void* g, void* l) {
    __builtin_amdgcn_global_load_lds(
        (const __attribute__((address_space(1))) unsigned int*)g,
        (__attribute__((address_space(3))) unsigned int*)l, 16, 0, 0);
}

// ---------------- K_pre: transpose_norm (512) | f2bf Wgk (2048) | Winp^T (512) | Wg_eff atomics (128)
__global__ __launch_bounds__(256) void k_pre(const float* __restrict__ x,
                                             const float* __restrict__ Wgk,
                                             const float* __restrict__ Winp,
                                             const float* __restrict__ Wg,
                                             const float* __restrict__ binp,
                                             const float* __restrict__ bg,
                                             u16* __restrict__ xtn,
                                             u16* __restrict__ wgkb,
                                             u16* __restrict__ winpT,
                                             float* __restrict__ wge,
                                             float* __restrict__ cg) {
    int bid = blockIdx.x, tid = threadIdx.x;
    if (bid < 512) {
        // x [32,1024,16,8] -> xtn[b][m][c] bf16, L2-normalized over c
        int b8 = bid >> 4, hh = bid & 15;
        __shared__ float tile[8][1032];
        __shared__ float inv[8];
        const float* src = x + (size_t)b8 * 1024 * 128 + hh * 8;
        #pragma unroll
        for (int r = 0; r < 4; ++r) {
            int c = tid * 4 + r;
            const float* p = src + (size_t)c * 128;
            float4 v0 = *(const float4*)(p);
            float4 v1 = *(const float4*)(p + 4);
            tile[0][c] = v0.x; tile[1][c] = v0.y; tile[2][c] = v0.z; tile[3][c] = v0.w;
            tile[4][c] = v1.x; tile[5][c] = v1.y; tile[6][c] = v1.z; tile[7][c] = v1.w;
        }
        __syncthreads();
        int w = tid >> 5, j = tid & 31;
        float s = 0.f;
        #pragma unroll 8
        for (int i = 0; i < 32; ++i) { float v = tile[w][i * 32 + j]; s += v * v; }
        #pragma unroll
        for (int m = 16; m; m >>= 1) s += __shfl_xor(s, m);
        if (j == 0) inv[w] = 1.0f / fmaxf(sqrtf(s), 1e-12f);
        __syncthreads();
        int b = b8 >> 3, t = b8 & 7;
        int c0 = tid * 4;
        for (int w2 = 0; w2 < 8; ++w2) {
            int m = t * 128 + hh * 8 + w2;
            float sc = inv[w2];
            u16* dst = xtn + ((size_t)b * 1024 + m) * 1024;
            ushort4 o;
            o.x = f2bf(tile[w2][c0 + 0] * sc);
            o.y = f2bf(tile[w2][c0 + 1] * sc);
            o.z = f2bf(tile[w2][c0 + 2] * sc);
            o.w = f2bf(tile[w2][c0 + 3] * sc);
            *(ushort4*)(dst + c0) = o;
        }
    } else if (bid < 2560) {
        int i = ((bid - 512) * 256 + tid) * 4;
        float4 v = *(const float4*)(Wgk + i);
        ushort4 o;
        o.x = f2bf(v.x); o.y = f2bf(v.y); o.z = f2bf(v.z); o.w = f2bf(v.w);
        *(ushort4*)(wgkb + i) = o;
    } else if (bid < 3072) {
        int tb = bid - 2560;            // 0..511
        int er = tb & 31, cr = tb >> 5; // e-tile(64), c-tile(64)
        __shared__ float tile[64][65];
        #pragma unroll
        for (int i = 0; i < 16; ++i) {
            int idx = tid + i * 256;
            int r = idx >> 6, c = idx & 63;
            tile[r][c] = Winp[(size_t)(er * 64 + r) * 1024 + cr * 64 + c];
        }
        __syncthreads();
        #pragma unroll
        for (int i = 0; i < 16; ++i) {
            int idx = tid + i * 256;
            int cc = idx >> 6, rr = idx & 63;
            winpT[(size_t)(cr * 64 + cc) * 2048 + er * 64 + rr] = f2bf(tile[rr][cc]);
        }
    } else {
        // Wg_eff[g][c] += sum_{e in es} Wg[g][e]*Winp[e][c]; cg[g] += Wg[g,:].b_inp (+bg)
        int t2 = bid - 3072;            // 0..127
        int cs = t2 & 3, es = t2 >> 2;  // c-seg(256), e-seg(64)
        __shared__ float wg_l[8][64];
        #pragma unroll
        for (int i = 0; i < 2; ++i) {
            int idx = tid + i * 256;
            wg_l[idx >> 6][idx & 63] = Wg[(size_t)(idx >> 6) * 2048 + es * 64 + (idx & 63)];
        }
        __syncthreads();
        int c = cs * 256 + tid;
        float acc[8] = {};
        #pragma unroll 4
        for (int e = 0; e < 64; ++e) {
            float v = Winp[(size_t)(es * 64 + e) * 1024 + c];
            #pragma unroll
            for (int g = 0; g < 8; ++g) acc[g] += wg_l[g][e] * v;
        }
        #pragma unroll
        for (int g = 0; g < 8; ++g) atomicAdd(&wge[g * 1024 + c], acc[g]);
        if (cs == 0) {
            int g = tid >> 5, sub = tid & 31;
            float t = 0.f;
            for (int e = sub; e < 64; e += 32) t += wg_l[g][e] * binp[es * 64 + e];
            #pragma unroll
            for (int m = 16; m; m >>= 1) t += __shfl_xor(t, m);
            if (sub == 0) {
                if (es == 0) t += bg[g];
                atomicAdd(&cg[g], t);
            }
        }
    }
}

// ---------------- K2: bf16 MFMA GEMM (BT), BK=128, 8 waves, ring-2 LDS, counted vmcnt ----------------
// Both-sides chunk-XOR swizzle: LDS[row][c16] = G[row][c16 ^ (row&7)] via pre-swizzled global src.
// MODE 0: f32 out (+split-K z). MODE 3: em1 = exp(acc)-1 bf16 out; atomic column sums ssum/sagm.
template <int BM, int BN, int WC, int MODE>
__global__ __launch_bounds__(512) void k_mfma_gemm(
    const u16* __restrict__ A, const u16* __restrict__ B,
    float* __restrict__ Cf, u16* __restrict__ Cb,
    const float* __restrict__ agT, float* __restrict__ ssum, float* __restrict__ sagm,
    int Kld, int Kloop, int N,
    long long zA, long long zB, long long zC)
{
    constexpr int WR = 8 / WC;
    constexpr int WM = BM / WR;
    constexpr int WN = BN / WC;
    constexpr int MR = WM / 16;
    constexpr int NR = WN / 16;
    constexpr int QA = (BM * 128) / 4096;   // staging rounds (512 thr x 16B)
    constexpr int QB = (BN * 128) / 4096;
    constexpr int S = QA + QB;
    __shared__ u16 As[2][BM * 128];
    __shared__ u16 Bs[2][BN * 128];
    int bz = blockIdx.z;
    A += (size_t)bz * zA; B += (size_t)bz * zB;
    int tid = threadIdx.x, lane = tid & 63, wave = tid >> 6;
    int wr = wave / WC, wc = wave % WC;
    int i0 = blockIdx.y * BM, j0 = blockIdx.x * BN;
    int fr = lane & 15, fg = lane >> 4;
    f32x4 acc[MR][NR] = {};

    int srcOff = ((tid & 15) ^ ((tid >> 4) & 7)) * 8;   // pre-swizzled global chunk (16 chunks/row)

    auto stage = [&](int buf, int t) {
        int kt = t * 128;
        #pragma unroll
        for (int q = 0; q < QA; ++q) {
            int row = (q * 512 + tid) >> 4;
            gload16(A + (size_t)(i0 + row) * Kld + kt + srcOff,
                    &As[buf][(q * 512 + wave * 64) * 8]);
        }
        #pragma unroll
        for (int q = 0; q < QB; ++q) {
            int row = (q * 512 + tid) >> 4;
            gload16(B + (size_t)(j0 + row) * Kld + kt + srcOff,
                    &Bs[buf][(q * 512 + wave * 64) * 8]);
        }
    };
    auto compute = [&](int buf) {
        #pragma unroll
        for (int h = 0; h < 4; ++h) {               // four K=32 slices of BK=128
            bf16x8 af[MR], bv[NR];
            #pragma unroll
            for (int mi = 0; mi < MR; ++mi) {
                int row = wr * WM + mi * 16 + fr;
                af[mi] = *(const bf16x8*)&As[buf][row * 128 + (((h * 4 + fg) ^ (fr & 7)) * 8)];
            }
            #pragma unroll
            for (int ni = 0; ni < NR; ++ni) {
                int row = wc * WN + ni * 16 + fr;
                bv[ni] = *(const bf16x8*)&Bs[buf][row * 128 + (((h * 4 + fg) ^ (fr & 7)) * 8)];
            }
            #pragma unroll
            for (int mi = 0; mi < MR; ++mi)
                #pragma unroll
                for (int ni = 0; ni < NR; ++ni)
                    acc[mi][ni] = __builtin_amdgcn_mfma_f32_16x16x32_bf16(
                        af[mi], bv[ni], acc[mi][ni], 0, 0, 0);
        }
    };

    int nk = Kloop >> 7;
    stage(0, 0);
    int cur = 0;
    for (int t = 0; t < nk; ++t) {
        if (t + 1 < nk) {
            stage(cur ^ 1, t + 1);
            if constexpr (S == 8)      asm volatile("s_waitcnt vmcnt(8)" ::: "memory");
            else if constexpr (S == 6) asm volatile("s_waitcnt vmcnt(6)" ::: "memory");
            else                       asm volatile("s_waitcnt vmcnt(4)" ::: "memory");
        } else {
            asm volatile("s_waitcnt vmcnt(0)" ::: "memory");
        }
        __builtin_amdgcn_s_barrier();
        __builtin_amdgcn_sched_barrier(0);
        compute(cur);
        __builtin_amdgcn_s_barrier();
        cur ^= 1;
    }

    // epilogue: C/D layout col = lane&15, row = (lane>>4)*4 + r  [m89]
    if constexpr (MODE == 3) {
        int g = blockIdx.y;             // BM=128 => one g per block
        int bcol = j0 >> 10;            // BN=128 => one b per block
        float ag2[NR];
        #pragma unroll
        for (int ni = 0; ni < NR; ++ni) {
            int col = j0 + wc * WN + ni * 16 + fr;
            ag2[ni] = agT[((size_t)bcol * 8 + g) * 1024 + (col & 1023)];
        }
        #pragma unroll
        for (int mi = 0; mi < MR; ++mi)
            #pragma unroll
            for (int r = 0; r < 4; ++r) {
                int row = i0 + wr * WM + mi * 16 + fg * 4 + r;
                float es = 0.f, sa = 0.f;
                #pragma unroll
                for (int ni = 0; ni < NR; ++ni) {
                    int col = j0 + wc * WN + ni * 16 + fr;
                    float e = expf(acc[mi][ni][r]);
                    es += e; sa += ag2[ni] * e;
                    Cb[(size_t)row * N + col] = f2bf(e - 1.f);
                }
                #pragma unroll
                for (int m = 8; m; m >>= 1) { es += __shfl_xor(es, m); sa += __shfl_xor(sa, m); }
                if (fr == 0) {
                    atomicAdd(&ssum[row * 4 + bcol], es);
                    atomicAdd(&sagm[row * 4 + bcol], sa);
                }
            }
    } else {
        float* C2 = Cf + (size_t)bz * zC;
        #pragma unroll
        for (int ni = 0; ni < NR; ++ni) {
            int col = j0 + wc * WN + ni * 16 + fr;
            #pragma unroll
            for (int mi = 0; mi < MR; ++mi)
                #pragma unroll
                for (int r = 0; r < 4; ++r) {
                    int row = i0 + wr * WM + mi * 16 + fg * 4 + r;
                    C2[(size_t)row * N + col] = acc[mi][ni][r];
                }
        }
    }
}

// ---------------- K_mid: wcred (1024 blocks) | agT (128 blocks) ----------------
__global__ __launch_bounds__(256) void k_mid(const float* __restrict__ wcp,
                                             u16* __restrict__ wcb,
                                             const u16* __restrict__ xtn,
                                             const float* __restrict__ wge,
                                             const float* __restrict__ cg,
                                             float* __restrict__ agT) {
    int bid = blockIdx.x, tid = threadIdx.x;
    if (bid < 1024) {
        int i = (bid * 256 + tid) * 4;
        float4 a = *(const float4*)(wcp + i);
        float4 b = *(const float4*)(wcp + 1048576 + i);
        float4 c = *(const float4*)(wcp + 2097152 + i);
        float4 d = *(const float4*)(wcp + 3145728 + i);
        ushort4 o;
        o.x = f2bf(a.x + b.x + c.x + d.x);
        o.y = f2bf(a.y + b.y + c.y + d.y);
        o.z = f2bf(a.z + b.z + c.z + d.z);
        o.w = f2bf(a.w + b.w + c.w + d.w);
        *(ushort4*)(wcb + i) = o;
    } else {
        // agT[b][g][m] = sigmoid(Wg_eff . xtn[b,m,:] + c_g)
        int t2 = bid - 1024;
        int b = t2 >> 5, ms = t2 & 31;
        int w = tid >> 6, lane = tid & 63;
        __shared__ float wgel[8192];
        __shared__ float cgl[8];
        #pragma unroll
        for (int i = 0; i < 8; ++i) {
            int idx = tid + i * 256;
            *(float4*)&wgel[idx * 4] = *(const float4*)&wge[idx * 4];
        }
        if (tid < 8) cgl[tid] = cg[tid];
        __syncthreads();
        for (int r = 0; r < 8; ++r) {
            int m = ms * 32 + w * 8 + r;
            const u16* xr = xtn + ((size_t)b * 1024 + m) * 1024;
            float acc[8] = {};
            #pragma unroll
            for (int i = 0; i < 2; ++i) {
                int c0 = i * 512 + lane * 8;
                bf16x8 hv = *(const bf16x8*)(xr + c0);
                float xf[8];
                #pragma unroll
                for (int j = 0; j < 8; ++j) xf[j] = bf2f((u16)hv[j]);
                #pragma unroll
                for (int g = 0; g < 8; ++g) {
                    float4 wa = *(const float4*)&wgel[g * 1024 + c0];
                    float4 wb = *(const float4*)&wgel[g * 1024 + c0 + 4];
                    acc[g] += xf[0] * wa.x + xf[1] * wa.y + xf[2] * wa.z + xf[3] * wa.w
                            + xf[4] * wb.x + xf[5] * wb.y + xf[6] * wb.z + xf[7] * wb.w;
                }
            }
            #pragma unroll
            for (int g = 0; g < 8; ++g)
                #pragma unroll
                for (int off = 32; off; off >>= 1) acc[g] += __shfl_xor(acc[g], off);
            if (lane < 8)
                agT[((size_t)b * 8 + lane) * 1024 + m] =
                    1.f / (1.f + expf(-(acc[lane] + cgl[lane])));
        }
    }
}

// ---------------- K_wf2: wf[b,g,m] = ag[m]*(C0 + sum_k c1[k]*em1[k,m]),  c1 = Wf/s;  u ----------------
__global__ __launch_bounds__(256) void k_wf2(const u16* __restrict__ em1,
                                             const float* __restrict__ ssum,
                                             const float* __restrict__ sagm,
                                             const float* __restrict__ Wf,
                                             const float* __restrict__ agT,
                                             float* __restrict__ wf, float* __restrict__ u) {
    int ms = blockIdx.x, bg = blockIdx.y;  // (8, 32)
    int b = bg >> 3, g = bg & 7;
    int tid = threadIdx.x;
    __shared__ float c1[128];
    __shared__ float part[256];
    __shared__ float c0s;
    if (tid < 128) {
        int gk = g * 128 + tid;
        float s = ssum[gk * 4 + b];
        float wfk = Wf[tid];
        float cv = wfk / s;
        c1[tid] = cv;
        part[tid] = cv;
        if (ms == 0) u[bg * 128 + tid] = wfk * sagm[gk * 4 + b] / s;
    } else part[tid] = 0.f;
    __syncthreads();
    for (int st = 128; st; st >>= 1) { if (tid < st) part[tid] += part[tid + st]; __syncthreads(); }
    if (tid == 0) c0s = part[0];
    __syncthreads();
    float C0 = c0s;
    int ml = tid & 127, kh = tid >> 7;
    const u16* base = em1 + (size_t)(g * 128 + kh * 64) * 4096 + b * 1024 + ms * 128;
    float acc = 0.f;
    #pragma unroll 4
    for (int k = 0; k < 64; ++k)
        acc += c1[kh * 64 + k] * bf2f(base[(size_t)k * 4096 + ml]);
    __syncthreads();
    part[tid] = acc;
    __syncthreads();
    if (tid < 128) {
        float agv = agT[((size_t)b * 8 + g) * 1024 + ms * 128 + tid];
        wf[(size_t)bg * 1024 + ms * 128 + tid] = (C0 + part[tid] + part[tid + 128]) * agv;
    }
}

// ---------------- K_wfx: wfxp[ms][b][g][c] = sum_{m in seg} wf[b,g,m]*xtn[b,m,c] ----------------
__global__ __launch_bounds__(256) void k_wfx(const u16* __restrict__ xtn,
                                             const float* __restrict__ wf,
                                             float* __restrict__ wfxp) {
    int cs = blockIdx.x, ms = blockIdx.y, b = blockIdx.z;  // (4,8,4)
    int tid = threadIdx.x;
    __shared__ float wfl[8][128];
    #pragma unroll
    for (int i = 0; i < 4; ++i) {
        int idx = tid + i * 256;
        wfl[idx >> 7][idx & 127] = wf[((size_t)b * 8 + (idx >> 7)) * 1024 + ms * 128 + (idx & 127)];
    }
    __syncthreads();
    int c = cs * 256 + tid;
    float acc[8] = {};
    for (int m = 0; m < 128; ++m) {
        float xv = bf2f(xtn[((size_t)b * 1024 + ms * 128 + m) * 1024 + c]);
        #pragma unroll
        for (int g = 0; g < 8; ++g) acc[g] += wfl[g][m] * xv;
    }
    #pragma unroll
    for (int g = 0; g < 8; ++g)
        wfxp[(((size_t)ms * 4 + b) * 8 + g) * 1024 + c] = acc[g];
}

// ---------------- K_vfpart: cs<8: vf += wfx . W_inp^T slice; cs==8: -u.cent + sw*b_inp ----------------
__global__ __launch_bounds__(256) void k_vfpart(const float* __restrict__ wfxp,
                                                const u16* __restrict__ winpT,
                                                const float* __restrict__ u,
                                                const float* __restrict__ cent,
                                                const float* __restrict__ binp,
                                                float* __restrict__ vfp) {
    int g = blockIdx.x, cs = blockIdx.y;  // (8, 9)
    int tid = threadIdx.x;
    if (cs < 8) {
        __shared__ float wfx_l[4][128];
        #pragma unroll
        for (int i = 0; i < 2; ++i) {
            int idx = tid + i * 256;
            int bb = idx >> 7, c2 = idx & 127;
            float s = 0.f;
            #pragma unroll
            for (int msq = 0; msq < 8; ++msq)
                s += wfxp[(((size_t)msq * 4 + bb) * 8 + g) * 1024 + cs * 128 + c2];
            wfx_l[bb][c2] = s;
        }
        __syncthreads();
        int d = tid;
        float acc[4] = {};
        for (int c2 = 0; c2 < 128; ++c2) {
            float wv = bf2f(winpT[(size_t)(cs * 128 + c2) * 2048 + g * 256 + d]);
            #pragma unroll
            for (int bb = 0; bb < 4; ++bb) acc[bb] += wfx_l[bb][c2] * wv;
        }
        #pragma unroll
        for (int bb = 0; bb < 4; ++bb)
            vfp[(((size_t)bb * 8 + g) * 9 + cs) * 256 + d] = acc[bb];
    } else {
        __shared__ float ul[4][128];
        __shared__ float swl[4];
        #pragma unroll
        for (int i = 0; i < 2; ++i) {
            int idx = tid + i * 256;
            ul[idx >> 7][idx & 127] = u[((size_t)(idx >> 7) * 8 + g) * 128 + (idx & 127)];
        }
        __syncthreads();
        if (tid < 4) {
            float s = 0.f;
            for (int k = 0; k < 128; ++k) s += ul[tid][k];
            swl[tid] = s;
        }
        __syncthreads();
        int d = tid;
        float acc[4] = {};
        for (int k = 0; k < 128; ++k) {
            float cv = cent[k * 256 + d];
            #pragma unroll
            for (int bb = 0; bb < 4; ++bb) acc[bb] -= ul[bb][k] * cv;
        }
        float bi = binp[g * 256 + d];
        #pragma unroll
        for (int bb = 0; bb < 4; ++bb)
            vfp[(((size_t)bb * 8 + g) * 9 + 8) * 256 + d] = acc[bb] + swl[bb] * bi;
    }
}

// ---------------- K_fin: finalize vf -> rank-8 NS -> triuvec output (fused, grid=4) ----------------
#define MM8(DST, P, Q) do { if (act) { float s_ = 0.f; \
    _Pragma("unroll") \
    for (int l_ = 0; l_ < 8; ++l_) s_ += P[ii][l_] * Q[l_][jj]; \
    DST[ii][jj] = s_; } __syncthreads(); } while (0)

__global__ __launch_bounds__(256) void k_fin(const float* __restrict__ vfp,
                                             const float* __restrict__ bf,
                                             float* __restrict__ out) {
    int b = blockIdx.x;
    int tid = threadIdx.x, d = tid;
    __shared__ float Vl[256][9];
    __shared__ float4 Vl4a[256], Vl4b[256];
    __shared__ float red[256];
    __shared__ float Sp[4][64];
    __shared__ float Sm[8][8], W1[8][8], W2[8][8], YmL[8][8], ZmL[8][8], ZYL[8][8], FmL[8][8];
    float bfv = bf[0];
    float vfl[8];
    #pragma unroll
    for (int g = 0; g < 8; ++g) {
        float acc = 0.f;
        for (int mc = 0; mc < 9; ++mc)
            acc += vfp[(((size_t)b * 8 + g) * 9 + mc) * 256 + d];
        vfl[g] = acc + bfv;
    }
    float mean = 0.f;
    #pragma unroll
    for (int g = 0; g < 8; ++g) mean += vfl[g];
    mean *= 0.125f;
    float trp = 0.f;
    #pragma unroll
    for (int g = 0; g < 8; ++g) { float v = vfl[g] - mean; Vl[d][g] = v; vfl[g] = v; trp += v * v; }
    Vl4a[d] = make_float4(vfl[0], vfl[1], vfl[2], vfl[3]);
    Vl4b[d] = make_float4(vfl[4], vfl[5], vfl[6], vfl[7]);
    red[tid] = trp;
    __syncthreads();
    for (int s = 128; s > 0; s >>= 1) { if (tid < s) red[tid] += red[tid + s]; __syncthreads(); }
    float tr = red[0] * 0.125f;  // trace(cov)
    // parallel Sm: 4 dd-quarters x 64 (ii,jj)
    {
        int q = tid >> 6, l = tid & 63;
        int si = l >> 3, sj = l & 7;
        float sv = 0.f;
        for (int dd = q * 64; dd < q * 64 + 64; ++dd) sv += Vl[dd][si] * Vl[dd][sj];
        Sp[q][l] = sv;
    }
    __syncthreads();
    bool act = tid < 64;
    int ii = (tid >> 3) & 7, jj = tid & 7;
    if (act) Sm[ii][jj] = (Sp[0][tid] + Sp[1][tid] + Sp[2][tid] + Sp[3][tid]) / (8.f * tr);
    __syncthreads();
    // mat = a*I + U B U^T, S = U^T U; product (a,P)(c,Q) = (ac, aQ+cP+P S Q)
    if (act) {
        YmL[ii][jj] = (ii == jj ? 1.5f : 0.f) - 0.5f * Sm[ii][jj];
        ZmL[ii][jj] = (ii == jj ? -0.5f : 0.f);
    }
    __syncthreads();
    float ya = 0.f, za = 1.5f;
    MM8(W1, Sm, YmL);
    MM8(W2, ZmL, W1);
    float pa = za * ya;
    if (act) ZYL[ii][jj] = -0.5f * (za * YmL[ii][jj] + ya * ZmL[ii][jj] + W2[ii][jj]);
    __syncthreads();
    float zya = 1.5f - 0.5f * pa;
    MM8(W1, Sm, ZYL);
    MM8(W2, YmL, W1);
    if (act) YmL[ii][jj] = ya * ZYL[ii][jj] + zya * YmL[ii][jj] + W2[ii][jj];
    __syncthreads();
    ya = ya * zya;
    MM8(W1, Sm, ZmL);
    MM8(W2, ZYL, W1);
    if (act) ZmL[ii][jj] = zya * ZmL[ii][jj] + za * ZYL[ii][jj] + W2[ii][jj];
    __syncthreads();
    za = zya * za;
    MM8(W1, Sm, YmL);
    MM8(W2, ZmL, W1);
    float p2a = za * ya;
    if (act) ZYL[ii][jj] = za * YmL[ii][jj] + ya * ZmL[ii][jj] + W2[ii][jj];
    __syncthreads();
    MM8(W1, Sm, ZYL);
    MM8(W2, YmL, W1);
    if (act) FmL[ii][jj] = 0.5f * ((3.f - p2a) * YmL[ii][jj] - ya * ZYL[ii][jj] - W2[ii][jj]);
    __syncthreads();
    float fa = 0.5f * ya * (3.f - p2a);
    float sqtr = sqrtf(tr);
    float scaleF = 1.f / (8.f * sqtr);
    float wrj[8];
    #pragma unroll
    for (int jo = 0; jo < 8; ++jo) {
        float sv = 0.f;
        #pragma unroll
        for (int i = 0; i < 8; ++i) sv += vfl[i] * FmL[i][jo];
        wrj[jo] = sv * scaleF;
    }
    float s0v = fa * sqtr;
    // triuvec output: R[d,e] = s0*delta(d,e) + Wrow[d,:].Vc[e,:]
    size_t base = (size_t)b * 32896 + (size_t)d * 256 - ((size_t)d * (d - 1)) / 2 - d;
    for (int e = d; e < 256; ++e) {
        float4 va = Vl4a[e], vb = Vl4b[e];
        float v = wrj[0] * va.x + wrj[1] * va.y + wrj[2] * va.z + wrj[3] * va.w
                + wrj[4] * vb.x + wrj[5] * vb.y + wrj[6] * vb.z + wrj[7] * vb.w;
        if (e == d) v += s0v;
        out[base + e] = v;
    }
}

extern "C" void kernel_launch(void* const* d_in, const int* in_sizes, int n_in,
                              void* d_out, int out_size, void* d_ws, size_t ws_size,
                              hipStream_t stream) {
    const float* x    = (const float*)d_in[0];
    const float* cent = (const float*)d_in[1];
    const float* Winp = (const float*)d_in[2];
    const float* binp = (const float*)d_in[3];
    const float* Wg   = (const float*)d_in[4];
    const float* bg   = (const float*)d_in[5];
    const float* Wgk  = (const float*)d_in[6];
    const float* Wf   = (const float*)d_in[8];
    const float* bf   = (const float*)d_in[9];
    float* out = (float*)d_out;
    char* wsb = (char*)d_ws;

    // byte-offset workspace layout
    u16*   xtnb  = (u16*)(wsb);                          // [4096][1024] bf16, 8 MB
    u16*   ltb   = (u16*)(wsb + (8ull << 20));           // em1 [1024][4096] bf16, 8 MB
    u16*   wgkb  = (u16*)(wsb + (16ull << 20));          // [1024][2048] bf16, 4 MB
    u16*   winpT = (u16*)(wsb + (20ull << 20));          // [1024][2048] bf16, 4 MB
    float* wcp   = (float*)(wsb + (24ull << 20));        // [4][1024][1024] f32, 16 MB
    u16*   wcb   = (u16*)(wsb + (40ull << 20));          // [1024][1024] bf16, 2 MB
    float* misc  = (float*)(wsb + (42ull << 20));
    float* wge   = misc;                 // [8][1024]   (atomic)
    float* cg    = wge + 8192;           // [8]         (atomic)
    float* ssum  = cg + 8;               // [1024][4]   (atomic)
    float* sagm  = ssum + 4096;          // [1024][4]   (atomic)
    // memset covers wge..sagm = 16392 floats
    float* agT   = sagm + 4096;          // [4][8][1024]
    float* u     = agT + 32768;          // [32][128]
    float* wf    = u + 4096;             // [32][1024]
    float* wfxp  = wf + 32768;           // [8][4][8][1024]
    float* vfp   = wfxp + 262144;        // [4][8][9][256]

    hipMemsetAsync(misc, 0, 16392 * sizeof(float), stream);
    k_pre<<<3200, 256, 0, stream>>>(x, Wgk, Winp, Wg, binp, bg, xtnb, wgkb, winpT, wge, cg);
    // Wc = W_gk @ W_inp: M=1024, N=1024, K=2048 split-K (4 x 512), BK=128 -> f32 partials
    k_mfma_gemm<128, 128, 4, 0><<<dim3(8, 8, 4), 512, 0, stream>>>(
        wgkb, winpT, wcp, nullptr, nullptr, nullptr, nullptr,
        2048, 512, 1024, 512LL, 512LL, 1048576LL);
    k_mid<<<1152, 256, 0, stream>>>(wcp, wcb, xtnb, wge, cg, agT);
    // logits: em1[gk][b*1024+m] = exp(Wc @ xtn^T) - 1 (bf16) + atomic ssum/sagm
    // (biases dropped: constant per gk-row, softmax over m shift-invariant; no max needed,
    //  |logit| <= ||Wc_row|| < 1)
    k_mfma_gemm<128, 128, 4, 3><<<dim3(32, 8, 1), 512, 0, stream>>>(
        wcb, xtnb, nullptr, ltb, agT, ssum, sagm,
        1024, 1024, 4096, 0, 0, 0);
    k_wf2<<<dim3(8, 32), 256, 0, stream>>>(ltb, ssum, sagm, Wf, agT, wf, u);
    k_wfx<<<dim3(4, 8, 4), 256, 0, stream>>>(xtnb, wf, wfxp);
    k_vfpart<<<dim3(8, 9), 256, 0, stream>>>(wfxp, winpT, u, cent, binp, vfp);
    k_fin<<<4, 256, 0, stream>>>(vfp, bf, out);
}

// Round 11
// 145.277 us; speedup vs baseline: 1.0842x; 1.0842x over previous
//
#include <hip/hip_runtime.h>
#include <math.h>

typedef float f32x4 __attribute__((ext_vector_type(4)));
typedef short bf16x8 __attribute__((ext_vector_type(8)));
typedef unsigned short u16;

__device__ __forceinline__ u16 f2bf(float f) {
    unsigned u = __builtin_bit_cast(unsigned, f);
    u += 0x7fff + ((u >> 16) & 1);   // RNE
    return (u16)(u >> 16);
}
__device__ __forceinline__ float bf2f(u16 s) {
    unsigned v = ((unsigned)s) << 16;
    return __builtin_bit_cast(float, v);
}
__device__ __forceinline__ void gload16(const void* g, void* l) {
    __builtin_amdgcn_global_load_lds(
        (const __attribute__((address_space(1))) unsigned int*)g,
        (__attribute__((address_space(3))) unsigned int*)l, 16, 0, 0);
}

// ---------------- K_pre: transpose_norm (512) | f2bf Wgk (2048) | Winp^T (512) | Wg_eff atomics (128)
__global__ __launch_bounds__(256) void k_pre(const float* __restrict__ x,
                                             const float* __restrict__ Wgk,
                                             const float* __restrict__ Winp,
                                             const float* __restrict__ Wg,
                                             const float* __restrict__ binp,
                                             const float* __restrict__ bg,
                                             u16* __restrict__ xtn,
                                             u16* __restrict__ wgkb,
                                             u16* __restrict__ winpT,
                                             float* __restrict__ wge,
                                             float* __restrict__ cg) {
    int bid = blockIdx.x, tid = threadIdx.x;
    if (bid < 512) {
        // x [32,1024,16,8] -> xtn[b][m][c] bf16, L2-normalized over c
        int b8 = bid >> 4, hh = bid & 15;
        __shared__ float tile[8][1032];
        __shared__ float inv[8];
        const float* src = x + (size_t)b8 * 1024 * 128 + hh * 8;
        #pragma unroll
        for (int r = 0; r < 4; ++r) {
            int c = tid * 4 + r;
            const float* p = src + (size_t)c * 128;
            float4 v0 = *(const float4*)(p);
            float4 v1 = *(const float4*)(p + 4);
            tile[0][c] = v0.x; tile[1][c] = v0.y; tile[2][c] = v0.z; tile[3][c] = v0.w;
            tile[4][c] = v1.x; tile[5][c] = v1.y; tile[6][c] = v1.z; tile[7][c] = v1.w;
        }
        __syncthreads();
        int w = tid >> 5, j = tid & 31;
        float s = 0.f;
        #pragma unroll 8
        for (int i = 0; i < 32; ++i) { float v = tile[w][i * 32 + j]; s += v * v; }
        #pragma unroll
        for (int m = 16; m; m >>= 1) s += __shfl_xor(s, m);
        if (j == 0) inv[w] = 1.0f / fmaxf(sqrtf(s), 1e-12f);
        __syncthreads();
        int b = b8 >> 3, t = b8 & 7;
        int c0 = tid * 4;
        for (int w2 = 0; w2 < 8; ++w2) {
            int m = t * 128 + hh * 8 + w2;
            float sc = inv[w2];
            u16* dst = xtn + ((size_t)b * 1024 + m) * 1024;
            ushort4 o;
            o.x = f2bf(tile[w2][c0 + 0] * sc);
            o.y = f2bf(tile[w2][c0 + 1] * sc);
            o.z = f2bf(tile[w2][c0 + 2] * sc);
            o.w = f2bf(tile[w2][c0 + 3] * sc);
            *(ushort4*)(dst + c0) = o;
        }
    } else if (bid < 2560) {
        int i = ((bid - 512) * 256 + tid) * 4;
        float4 v = *(const float4*)(Wgk + i);
        ushort4 o;
        o.x = f2bf(v.x); o.y = f2bf(v.y); o.z = f2bf(v.z); o.w = f2bf(v.w);
        *(ushort4*)(wgkb + i) = o;
    } else if (bid < 3072) {
        int tb = bid - 2560;            // 0..511
        int er = tb & 31, cr = tb >> 5; // e-tile(64), c-tile(64)
        __shared__ float tile[64][65];
        #pragma unroll
        for (int i = 0; i < 16; ++i) {
            int idx = tid + i * 256;
            int r = idx >> 6, c = idx & 63;
            tile[r][c] = Winp[(size_t)(er * 64 + r) * 1024 + cr * 64 + c];
        }
        __syncthreads();
        #pragma unroll
        for (int i = 0; i < 16; ++i) {
            int idx = tid + i * 256;
            int cc = idx >> 6, rr = idx & 63;
            winpT[(size_t)(cr * 64 + cc) * 2048 + er * 64 + rr] = f2bf(tile[rr][cc]);
        }
    } else {
        // Wg_eff[g][c] += sum_{e in es} Wg[g][e]*Winp[e][c]; cg[g] += Wg[g,:].b_inp (+bg)
        int t2 = bid - 3072;            // 0..127
        int cs = t2 & 3, es = t2 >> 2;  // c-seg(256), e-seg(64)
        __shared__ float wg_l[8][64];
        #pragma unroll
        for (int i = 0; i < 2; ++i) {
            int idx = tid + i * 256;
            wg_l[idx >> 6][idx & 63] = Wg[(size_t)(idx >> 6) * 2048 + es * 64 + (idx & 63)];
        }
        __syncthreads();
        int c = cs * 256 + tid;
        float acc[8] = {};
        #pragma unroll 4
        for (int e = 0; e < 64; ++e) {
            float v = Winp[(size_t)(es * 64 + e) * 1024 + c];
            #pragma unroll
            for (int g = 0; g < 8; ++g) acc[g] += wg_l[g][e] * v;
        }
        #pragma unroll
        for (int g = 0; g < 8; ++g) atomicAdd(&wge[g * 1024 + c], acc[g]);
        if (cs == 0) {
            int g = tid >> 5, sub = tid & 31;
            float t = 0.f;
            for (int e = sub; e < 64; e += 32) t += wg_l[g][e] * binp[es * 64 + e];
            #pragma unroll
            for (int m = 16; m; m >>= 1) t += __shfl_xor(t, m);
            if (sub == 0) {
                if (es == 0) t += bg[g];
                atomicAdd(&cg[g], t);
            }
        }
    }
}

// ---------------- K2: bf16 MFMA GEMM (BT), 64x64 tile, BK=64, 4 waves (2x2), ring-2,
// counted vmcnt, both-sides chunk-XOR swizzle (the R6/R7 0-conflict scheme).
// 32 KB LDS + launch_bounds(256,4) -> 4 blocks/CU co-resident (the overlap that hides the
// 2-phase stall, per m114). MODE 0: f32 out (+split-K z). MODE 3: em1=exp(acc)-1 bf16 out
// + atomic column sums ssum/sagm.
template <int MODE>
__global__ __launch_bounds__(256, 4) void k_mfma_gemm(
    const u16* __restrict__ A, const u16* __restrict__ B,
    float* __restrict__ Cf, u16* __restrict__ Cb,
    const float* __restrict__ agT, float* __restrict__ ssum, float* __restrict__ sagm,
    int Kld, int Kloop, int N,
    long long zA, long long zB, long long zC)
{
    constexpr int MR = 2, NR = 2;       // wave-tile 32x32 of 16x16 frags
    __shared__ u16 As[2][64 * 64];
    __shared__ u16 Bs[2][64 * 64];
    int bz = blockIdx.z;
    A += (size_t)bz * zA; B += (size_t)bz * zB;
    int tid = threadIdx.x, lane = tid & 63, wave = tid >> 6;
    int wr = wave >> 1, wc = wave & 1;
    int i0 = blockIdx.y * 64, j0 = blockIdx.x * 64;
    int fr = lane & 15, fg = lane >> 4;
    f32x4 acc[MR][NR] = {};

    int srcOff = ((tid & 7) ^ ((tid >> 3) & 7)) * 8;   // pre-swizzled global chunk (8 x 16B/row)
    int srow = tid >> 3;                               // row within 32-row staging round

    auto stage = [&](int buf, int t) {
        int kt = t * 64;
        #pragma unroll
        for (int q = 0; q < 2; ++q)
            gload16(A + (size_t)(i0 + q * 32 + srow) * Kld + kt + srcOff,
                    &As[buf][(q * 256 + wave * 64) * 8]);
        #pragma unroll
        for (int q = 0; q < 2; ++q)
            gload16(B + (size_t)(j0 + q * 32 + srow) * Kld + kt + srcOff,
                    &Bs[buf][(q * 256 + wave * 64) * 8]);
    };
    auto compute = [&](int buf) {
        #pragma unroll
        for (int h = 0; h < 2; ++h) {               // two K=32 halves of BK=64
            bf16x8 af[MR], bv[NR];
            #pragma unroll
            for (int mi = 0; mi < MR; ++mi) {
                int row = wr * 32 + mi * 16 + fr;
                af[mi] = *(const bf16x8*)&As[buf][row * 64 + (((h * 4 + fg) ^ (fr & 7)) * 8)];
            }
            #pragma unroll
            for (int ni = 0; ni < NR; ++ni) {
                int row = wc * 32 + ni * 16 + fr;
                bv[ni] = *(const bf16x8*)&Bs[buf][row * 64 + (((h * 4 + fg) ^ (fr & 7)) * 8)];
            }
            #pragma unroll
            for (int mi = 0; mi < MR; ++mi)
                #pragma unroll
                for (int ni = 0; ni < NR; ++ni)
                    acc[mi][ni] = __builtin_amdgcn_mfma_f32_16x16x32_bf16(
                        af[mi], bv[ni], acc[mi][ni], 0, 0, 0);
        }
    };

    int nk = Kloop >> 6;
    stage(0, 0);
    int cur = 0;
    for (int t = 0; t < nk; ++t) {
        if (t + 1 < nk) {
            stage(cur ^ 1, t + 1);                       // 4 loads/thread into free buf
            asm volatile("s_waitcnt vmcnt(4)" ::: "memory");  // own loads for buf cur done
        } else {
            asm volatile("s_waitcnt vmcnt(0)" ::: "memory");
        }
        __builtin_amdgcn_s_barrier();
        __builtin_amdgcn_sched_barrier(0);
        compute(cur);
        __builtin_amdgcn_s_barrier();
        cur ^= 1;
    }

    // epilogue: C/D layout col = lane&15, row = (lane>>4)*4 + r  [m89]
    if constexpr (MODE == 3) {
        int bcol = j0 >> 10;            // one b per block (BN=64)
        float ag2[NR];
        #pragma unroll
        for (int ni = 0; ni < NR; ++ni) {
            int col = j0 + wc * 32 + ni * 16 + fr;
            int g = i0 >> 7;            // BM=64: block spans one g (i0 multiple of 64, g = row>>7)
            ag2[ni] = agT[((size_t)bcol * 8 + g) * 1024 + (col & 1023)];
        }
        #pragma unroll
        for (int mi = 0; mi < MR; ++mi)
            #pragma unroll
            for (int r = 0; r < 4; ++r) {
                int row = i0 + wr * 32 + mi * 16 + fg * 4 + r;
                float es = 0.f, sa = 0.f;
                #pragma unroll
                for (int ni = 0; ni < NR; ++ni) {
                    int col = j0 + wc * 32 + ni * 16 + fr;
                    float e = expf(acc[mi][ni][r]);
                    es += e; sa += ag2[ni] * e;
                    Cb[(size_t)row * N + col] = f2bf(e - 1.f);
                }
                #pragma unroll
                for (int m = 8; m; m >>= 1) { es += __shfl_xor(es, m); sa += __shfl_xor(sa, m); }
                if (fr == 0) {
                    atomicAdd(&ssum[row * 4 + bcol], es);
                    atomicAdd(&sagm[row * 4 + bcol], sa);
                }
            }
    } else {
        float* C2 = Cf + (size_t)bz * zC;
        #pragma unroll
        for (int ni = 0; ni < NR; ++ni) {
            int col = j0 + wc * 32 + ni * 16 + fr;
            #pragma unroll
            for (int mi = 0; mi < MR; ++mi)
                #pragma unroll
                for (int r = 0; r < 4; ++r) {
                    int row = i0 + wr * 32 + mi * 16 + fg * 4 + r;
                    C2[(size_t)row * N + col] = acc[mi][ni][r];
                }
        }
    }
}

// ---------------- K_mid: wcred (1024 blocks) | agT (128 blocks) ----------------
__global__ __launch_bounds__(256) void k_mid(const float* __restrict__ wcp,
                                             u16* __restrict__ wcb,
                                             const u16* __restrict__ xtn,
                                             const float* __restrict__ wge,
                                             const float* __restrict__ cg,
                                             float* __restrict__ agT) {
    int bid = blockIdx.x, tid = threadIdx.x;
    if (bid < 1024) {
        int i = (bid * 256 + tid) * 4;
        float4 a = *(const float4*)(wcp + i);
        float4 b = *(const float4*)(wcp + 1048576 + i);
        float4 c = *(const float4*)(wcp + 2097152 + i);
        float4 d = *(const float4*)(wcp + 3145728 + i);
        ushort4 o;
        o.x = f2bf(a.x + b.x + c.x + d.x);
        o.y = f2bf(a.y + b.y + c.y + d.y);
        o.z = f2bf(a.z + b.z + c.z + d.z);
        o.w = f2bf(a.w + b.w + c.w + d.w);
        *(ushort4*)(wcb + i) = o;
    } else {
        // agT[b][g][m] = sigmoid(Wg_eff . xtn[b,m,:] + c_g)
        int t2 = bid - 1024;
        int b = t2 >> 5, ms = t2 & 31;
        int w = tid >> 6, lane = tid & 63;
        __shared__ float wgel[8192];
        __shared__ float cgl[8];
        #pragma unroll
        for (int i = 0; i < 8; ++i) {
            int idx = tid + i * 256;
            *(float4*)&wgel[idx * 4] = *(const float4*)&wge[idx * 4];
        }
        if (tid < 8) cgl[tid] = cg[tid];
        __syncthreads();
        for (int r = 0; r < 8; ++r) {
            int m = ms * 32 + w * 8 + r;
            const u16* xr = xtn + ((size_t)b * 1024 + m) * 1024;
            float acc[8] = {};
            #pragma unroll
            for (int i = 0; i < 2; ++i) {
                int c0 = i * 512 + lane * 8;
                bf16x8 hv = *(const bf16x8*)(xr + c0);
                float xf[8];
                #pragma unroll
                for (int j = 0; j < 8; ++j) xf[j] = bf2f((u16)hv[j]);
                #pragma unroll
                for (int g = 0; g < 8; ++g) {
                    float4 wa = *(const float4*)&wgel[g * 1024 + c0];
                    float4 wb = *(const float4*)&wgel[g * 1024 + c0 + 4];
                    acc[g] += xf[0] * wa.x + xf[1] * wa.y + xf[2] * wa.z + xf[3] * wa.w
                            + xf[4] * wb.x + xf[5] * wb.y + xf[6] * wb.z + xf[7] * wb.w;
                }
            }
            #pragma unroll
            for (int g = 0; g < 8; ++g)
                #pragma unroll
                for (int off = 32; off; off >>= 1) acc[g] += __shfl_xor(acc[g], off);
            if (lane < 8)
                agT[((size_t)b * 8 + lane) * 1024 + m] =
                    1.f / (1.f + expf(-(acc[lane] + cgl[lane])));
        }
    }
}

// ---------------- K_wf2: wf[b,g,m] = ag[m]*(C0 + sum_k c1[k]*em1[k,m]),  c1 = Wf/s;  u ----------------
__global__ __launch_bounds__(256) void k_wf2(const u16* __restrict__ em1,
                                             const float* __restrict__ ssum,
                                             const float* __restrict__ sagm,
                                             const float* __restrict__ Wf,
                                             const float* __restrict__ agT,
                                             float* __restrict__ wf, float* __restrict__ u) {
    int ms = blockIdx.x, bg = blockIdx.y;  // (8, 32)
    int b = bg >> 3, g = bg & 7;
    int tid = threadIdx.x;
    __shared__ float c1[128];
    __shared__ float part[256];
    __shared__ float c0s;
    if (tid < 128) {
        int gk = g * 128 + tid;
        float s = ssum[gk * 4 + b];
        float wfk = Wf[tid];
        float cv = wfk / s;
        c1[tid] = cv;
        part[tid] = cv;
        if (ms == 0) u[bg * 128 + tid] = wfk * sagm[gk * 4 + b] / s;
    } else part[tid] = 0.f;
    __syncthreads();
    for (int st = 128; st; st >>= 1) { if (tid < st) part[tid] += part[tid + st]; __syncthreads(); }
    if (tid == 0) c0s = part[0];
    __syncthreads();
    float C0 = c0s;
    int ml = tid & 127, kh = tid >> 7;
    const u16* base = em1 + (size_t)(g * 128 + kh * 64) * 4096 + b * 1024 + ms * 128;
    float acc = 0.f;
    #pragma unroll 4
    for (int k = 0; k < 64; ++k)
        acc += c1[kh * 64 + k] * bf2f(base[(size_t)k * 4096 + ml]);
    __syncthreads();
    part[tid] = acc;
    __syncthreads();
    if (tid < 128) {
        float agv = agT[((size_t)b * 8 + g) * 1024 + ms * 128 + tid];
        wf[(size_t)bg * 1024 + ms * 128 + tid] = (C0 + part[tid] + part[tid + 128]) * agv;
    }
}

// ---------------- K_wfx: wfxp[ms][b][g][c] = sum_{m in seg} wf[b,g,m]*xtn[b,m,c] ----------------
__global__ __launch_bounds__(256) void k_wfx(const u16* __restrict__ xtn,
                                             const float* __restrict__ wf,
                                             float* __restrict__ wfxp) {
    int cs = blockIdx.x, ms = blockIdx.y, b = blockIdx.z;  // (4,8,4)
    int tid = threadIdx.x;
    __shared__ float wfl[8][128];
    #pragma unroll
    for (int i = 0; i < 4; ++i) {
        int idx = tid + i * 256;
        wfl[idx >> 7][idx & 127] = wf[((size_t)b * 8 + (idx >> 7)) * 1024 + ms * 128 + (idx & 127)];
    }
    __syncthreads();
    int c = cs * 256 + tid;
    float acc[8] = {};
    for (int m = 0; m < 128; ++m) {
        float xv = bf2f(xtn[((size_t)b * 1024 + ms * 128 + m) * 1024 + c]);
        #pragma unroll
        for (int g = 0; g < 8; ++g) acc[g] += wfl[g][m] * xv;
    }
    #pragma unroll
    for (int g = 0; g < 8; ++g)
        wfxp[(((size_t)ms * 4 + b) * 8 + g) * 1024 + c] = acc[g];
}

// ---------------- K_vfpart: cs<8: vf += wfx . W_inp^T slice; cs==8: -u.cent + sw*b_inp ----------------
__global__ __launch_bounds__(256) void k_vfpart(const float* __restrict__ wfxp,
                                                const u16* __restrict__ winpT,
                                                const float* __restrict__ u,
                                                const float* __restrict__ cent,
                                                const float* __restrict__ binp,
                                                float* __restrict__ vfp) {
    int g = blockIdx.x, cs = blockIdx.y;  // (8, 9)
    int tid = threadIdx.x;
    if (cs < 8) {
        __shared__ float wfx_l[4][128];
        #pragma unroll
        for (int i = 0; i < 2; ++i) {
            int idx = tid + i * 256;
            int bb = idx >> 7, c2 = idx & 127;
            float s = 0.f;
            #pragma unroll
            for (int msq = 0; msq < 8; ++msq)
                s += wfxp[(((size_t)msq * 4 + bb) * 8 + g) * 1024 + cs * 128 + c2];
            wfx_l[bb][c2] = s;
        }
        __syncthreads();
        int d = tid;
        float acc[4] = {};
        for (int c2 = 0; c2 < 128; ++c2) {
            float wv = bf2f(winpT[(size_t)(cs * 128 + c2) * 2048 + g * 256 + d]);
            #pragma unroll
            for (int bb = 0; bb < 4; ++bb) acc[bb] += wfx_l[bb][c2] * wv;
        }
        #pragma unroll
        for (int bb = 0; bb < 4; ++bb)
            vfp[(((size_t)bb * 8 + g) * 9 + cs) * 256 + d] = acc[bb];
    } else {
        __shared__ float ul[4][128];
        __shared__ float swl[4];
        #pragma unroll
        for (int i = 0; i < 2; ++i) {
            int idx = tid + i * 256;
            ul[idx >> 7][idx & 127] = u[((size_t)(idx >> 7) * 8 + g) * 128 + (idx & 127)];
        }
        __syncthreads();
        if (tid < 4) {
            float s = 0.f;
            for (int k = 0; k < 128; ++k) s += ul[tid][k];
            swl[tid] = s;
        }
        __syncthreads();
        int d = tid;
        float acc[4] = {};
        for (int k = 0; k < 128; ++k) {
            float cv = cent[k * 256 + d];
            #pragma unroll
            for (int bb = 0; bb < 4; ++bb) acc[bb] -= ul[bb][k] * cv;
        }
        float bi = binp[g * 256 + d];
        #pragma unroll
        for (int bb = 0; bb < 4; ++bb)
            vfp[(((size_t)bb * 8 + g) * 9 + 8) * 256 + d] = acc[bb] + swl[bb] * bi;
    }
}

// ---------------- K_fin: finalize vf -> rank-8 NS -> triuvec output (fused, grid=4) ----------------
#define MM8(DST, P, Q) do { if (act) { float s_ = 0.f; \
    _Pragma("unroll") \
    for (int l_ = 0; l_ < 8; ++l_) s_ += P[ii][l_] * Q[l_][jj]; \
    DST[ii][jj] = s_; } __syncthreads(); } while (0)

__global__ __launch_bounds__(256) void k_fin(const float* __restrict__ vfp,
                                             const float* __restrict__ bf,
                                             float* __restrict__ out) {
    int b = blockIdx.x;
    int tid = threadIdx.x, d = tid;
    __shared__ float Vl[256][9];
    __shared__ float4 Vl4a[256], Vl4b[256];
    __shared__ float red[256];
    __shared__ float Sp[4][64];
    __shared__ float Sm[8][8], W1[8][8], W2[8][8], YmL[8][8], ZmL[8][8], ZYL[8][8], FmL[8][8];
    float bfv = bf[0];
    float vfl[8];
    #pragma unroll
    for (int g = 0; g < 8; ++g) {
        float acc = 0.f;
        for (int mc = 0; mc < 9; ++mc)
            acc += vfp[(((size_t)b * 8 + g) * 9 + mc) * 256 + d];
        vfl[g] = acc + bfv;
    }
    float mean = 0.f;
    #pragma unroll
    for (int g = 0; g < 8; ++g) mean += vfl[g];
    mean *= 0.125f;
    float trp = 0.f;
    #pragma unroll
    for (int g = 0; g < 8; ++g) { float v = vfl[g] - mean; Vl[d][g] = v; vfl[g] = v; trp += v * v; }
    Vl4a[d] = make_float4(vfl[0], vfl[1], vfl[2], vfl[3]);
    Vl4b[d] = make_float4(vfl[4], vfl[5], vfl[6], vfl[7]);
    red[tid] = trp;
    __syncthreads();
    for (int s = 128; s > 0; s >>= 1) { if (tid < s) red[tid] += red[tid + s]; __syncthreads(); }
    float tr = red[0] * 0.125f;  // trace(cov)
    {
        int q = tid >> 6, l = tid & 63;
        int si = l >> 3, sj = l & 7;
        float sv = 0.f;
        for (int dd = q * 64; dd < q * 64 + 64; ++dd) sv += Vl[dd][si] * Vl[dd][sj];
        Sp[q][l] = sv;
    }
    __syncthreads();
    bool act = tid < 64;
    int ii = (tid >> 3) & 7, jj = tid & 7;
    if (act) Sm[ii][jj] = (Sp[0][tid] + Sp[1][tid] + Sp[2][tid] + Sp[3][tid]) / (8.f * tr);
    __syncthreads();
    if (act) {
        YmL[ii][jj] = (ii == jj ? 1.5f : 0.f) - 0.5f * Sm[ii][jj];
        ZmL[ii][jj] = (ii == jj ? -0.5f : 0.f);
    }
    __syncthreads();
    float ya = 0.f, za = 1.5f;
    MM8(W1, Sm, YmL);
    MM8(W2, ZmL, W1);
    float pa = za * ya;
    if (act) ZYL[ii][jj] = -0.5f * (za * YmL[ii][jj] + ya * ZmL[ii][jj] + W2[ii][jj]);
    __syncthreads();
    float zya = 1.5f - 0.5f * pa;
    MM8(W1, Sm, ZYL);
    MM8(W2, YmL, W1);
    if (act) YmL[ii][jj] = ya * ZYL[ii][jj] + zya * YmL[ii][jj] + W2[ii][jj];
    __syncthreads();
    ya = ya * zya;
    MM8(W1, Sm, ZmL);
    MM8(W2, ZYL, W1);
    if (act) ZmL[ii][jj] = zya * ZmL[ii][jj] + za * ZYL[ii][jj] + W2[ii][jj];
    __syncthreads();
    za = zya * za;
    MM8(W1, Sm, YmL);
    MM8(W2, ZmL, W1);
    float p2a = za * ya;
    if (act) ZYL[ii][jj] = za * YmL[ii][jj] + ya * ZmL[ii][jj] + W2[ii][jj];
    __syncthreads();
    MM8(W1, Sm, ZYL);
    MM8(W2, YmL, W1);
    if (act) FmL[ii][jj] = 0.5f * ((3.f - p2a) * YmL[ii][jj] - ya * ZYL[ii][jj] - W2[ii][jj]);
    __syncthreads();
    float fa = 0.5f * ya * (3.f - p2a);
    float sqtr = sqrtf(tr);
    float scaleF = 1.f / (8.f * sqtr);
    float wrj[8];
    #pragma unroll
    for (int jo = 0; jo < 8; ++jo) {
        float sv = 0.f;
        #pragma unroll
        for (int i = 0; i < 8; ++i) sv += vfl[i] * FmL[i][jo];
        wrj[jo] = sv * scaleF;
    }
    float s0v = fa * sqtr;
    size_t base = (size_t)b * 32896 + (size_t)d * 256 - ((size_t)d * (d - 1)) / 2 - d;
    for (int e = d; e < 256; ++e) {
        float4 va = Vl4a[e], vb = Vl4b[e];
        float v = wrj[0] * va.x + wrj[1] * va.y + wrj[2] * va.z + wrj[3] * va.w
                + wrj[4] * vb.x + wrj[5] * vb.y + wrj[6] * vb.z + wrj[7] * vb.w;
        if (e == d) v += s0v;
        out[base + e] = v;
    }
}

extern "C" void kernel_launch(void* const* d_in, const int* in_sizes, int n_in,
                              void* d_out, int out_size, void* d_ws, size_t ws_size,
                              hipStream_t stream) {
    const float* x    = (const float*)d_in[0];
    const float* cent = (const float*)d_in[1];
    const float* Winp = (const float*)d_in[2];
    const float* binp = (const float*)d_in[3];
    const float* Wg   = (const float*)d_in[4];
    const float* bg   = (const float*)d_in[5];
    const float* Wgk  = (const float*)d_in[6];
    const float* Wf   = (const float*)d_in[8];
    const float* bf   = (const float*)d_in[9];
    float* out = (float*)d_out;
    char* wsb = (char*)d_ws;

    // byte-offset workspace layout
    u16*   xtnb  = (u16*)(wsb);                          // [4096][1024] bf16, 8 MB
    u16*   ltb   = (u16*)(wsb + (8ull << 20));           // em1 [1024][4096] bf16, 8 MB
    u16*   wgkb  = (u16*)(wsb + (16ull << 20));          // [1024][2048] bf16, 4 MB
    u16*   winpT = (u16*)(wsb + (20ull << 20));          // [1024][2048] bf16, 4 MB
    float* wcp   = (float*)(wsb + (24ull << 20));        // [4][1024][1024] f32, 16 MB
    u16*   wcb   = (u16*)(wsb + (40ull << 20));          // [1024][1024] bf16, 2 MB
    float* misc  = (float*)(wsb + (42ull << 20));
    float* wge   = misc;                 // [8][1024]   (atomic)
    float* cg    = wge + 8192;           // [8]         (atomic)
    float* ssum  = cg + 8;               // [1024][4]   (atomic)
    float* sagm  = ssum + 4096;          // [1024][4]   (atomic)
    float* agT   = sagm + 4096;          // [4][8][1024]
    float* u     = agT + 32768;          // [32][128]
    float* wf    = u + 4096;             // [32][1024]
    float* wfxp  = wf + 32768;           // [8][4][8][1024]
    float* vfp   = wfxp + 262144;        // [4][8][9][256]

    hipMemsetAsync(misc, 0, 16392 * sizeof(float), stream);
    k_pre<<<3200, 256, 0, stream>>>(x, Wgk, Winp, Wg, binp, bg, xtnb, wgkb, winpT, wge, cg);
    // Wc = W_gk @ W_inp: M=1024, N=1024, K=2048 split-K (4 x 512), 64x64 tile -> 1024 blocks (4/CU)
    k_mfma_gemm<0><<<dim3(16, 16, 4), 256, 0, stream>>>(
        wgkb, winpT, wcp, nullptr, nullptr, nullptr, nullptr,
        2048, 512, 1024, 512LL, 512LL, 1048576LL);
    k_mid<<<1152, 256, 0, stream>>>(wcp, wcb, xtnb, wge, cg, agT);
    // logits: em1[gk][b*1024+m] = exp(Wc @ xtn^T) - 1 (bf16) + atomic ssum/sagm
    // M=1024, N=4096, K=1024, 64x64 tile -> 1024 blocks (4/CU)
    k_mfma_gemm<3><<<dim3(64, 16, 1), 256, 0, stream>>>(
        wcb, xtnb, nullptr, ltb, agT, ssum, sagm,
        1024, 1024, 4096, 0, 0, 0);
    k_wf2<<<dim3(8, 32), 256, 0, stream>>>(ltb, ssum, sagm, Wf, agT, wf, u);
    k_wfx<<<dim3(4, 8, 4), 256, 0, stream>>>(xtnb, wf, wfxp);
    k_vfpart<<<dim3(8, 9), 256, 0, stream>>>(wfxp, winpT, u, cent, binp, vfp);
    k_fin<<<4, 256, 0, stream>>>(vfp, bf, out);
}